// Round 1
// baseline (1031.753 us; speedup 1.0000x reference)
//
#include <hip/hip_runtime.h>

#define NEG_SLOPE 0.2f

__device__ __forceinline__ float lrelu(float x) { return x > 0.f ? x : NEG_SLOPE * x; }

// ---------------- Layer-1 init: h1pre = x @ W1 (128x4), alpha_s/alpha_d ----------------
__global__ void l1_init_kernel(const float* __restrict__ x,
                               const float* __restrict__ W1,
                               const float* __restrict__ a_s,
                               const float* __restrict__ a_d,
                               float* __restrict__ h,
                               float* __restrict__ as_,
                               float* __restrict__ ad_,
                               int N)
{
    __shared__ float Wl[512];
    for (int i = threadIdx.x; i < 512; i += blockDim.x) Wl[i] = W1[i];
    __syncthreads();
    int n = blockIdx.x * blockDim.x + threadIdx.x;
    if (n >= N) return;
    const float4* xr = (const float4*)(x + (size_t)n * 128);
    float a0 = 0.f, a1 = 0.f, a2 = 0.f, a3 = 0.f;
#pragma unroll 8
    for (int j = 0; j < 32; ++j) {
        float4 v = xr[j];
        const float* w = &Wl[j * 16];
        a0 += v.x * w[0] + v.y * w[4] + v.z * w[8]  + v.w * w[12];
        a1 += v.x * w[1] + v.y * w[5] + v.z * w[9]  + v.w * w[13];
        a2 += v.x * w[2] + v.y * w[6] + v.z * w[10] + v.w * w[14];
        a3 += v.x * w[3] + v.y * w[7] + v.z * w[11] + v.w * w[15];
    }
    ((float4*)h)[n] = make_float4(a0, a1, a2, a3);
    as_[n] = a0 * a_s[0] + a1 * a_s[1] + a2 * a_s[2] + a3 * a_s[3];
    ad_[n] = a0 * a_d[0] + a1 * a_d[1] + a2 * a_d[2] + a3 * a_d[3];
}

// ---------------- CSR build ----------------
__global__ void hist_kernel(const int* __restrict__ dst, int* __restrict__ deg, int E)
{
    int i = (blockIdx.x * blockDim.x + threadIdx.x) * 4;
    if (i + 3 < E) {
        int4 d = *(const int4*)(dst + i);
        atomicAdd(&deg[d.x], 1); atomicAdd(&deg[d.y], 1);
        atomicAdd(&deg[d.z], 1); atomicAdd(&deg[d.w], 1);
    } else {
        for (; i < E; ++i) atomicAdd(&deg[dst[i]], 1);
    }
}

__global__ void scan_part_kernel(const int* __restrict__ deg, int* __restrict__ part, int N)
{
    __shared__ int sh[256];
    int i = blockIdx.x * 256 + threadIdx.x;
    sh[threadIdx.x] = (i < N) ? deg[i] : 0;
    __syncthreads();
    for (int o = 128; o > 0; o >>= 1) {
        if (threadIdx.x < o) sh[threadIdx.x] += sh[threadIdx.x + o];
        __syncthreads();
    }
    if (threadIdx.x == 0) part[blockIdx.x] = sh[0];
}

// single block of 1024; requires nb <= 1024 (N <= 262144)
__global__ void scan_top_kernel(int* __restrict__ part, int nb, int* __restrict__ row, int N, int E)
{
    __shared__ int sh[1024];
    int v = (threadIdx.x < nb) ? part[threadIdx.x] : 0;
    sh[threadIdx.x] = v;
    __syncthreads();
    for (int o = 1; o < 1024; o <<= 1) {
        int u = (threadIdx.x >= o) ? sh[threadIdx.x - o] : 0;
        __syncthreads();
        sh[threadIdx.x] += u;
        __syncthreads();
    }
    if (threadIdx.x < nb) part[threadIdx.x] = sh[threadIdx.x] - v;  // exclusive block offsets
    if (threadIdx.x == 0) row[N] = E;
}

__global__ void scan_final_kernel(const int* __restrict__ deg, const int* __restrict__ part,
                                  int* __restrict__ row, int* __restrict__ cur, int N)
{
    __shared__ int sh[256];
    int i = blockIdx.x * 256 + threadIdx.x;
    int v = (i < N) ? deg[i] : 0;
    sh[threadIdx.x] = v;
    __syncthreads();
    for (int o = 1; o < 256; o <<= 1) {
        int u = (threadIdx.x >= o) ? sh[threadIdx.x - o] : 0;
        __syncthreads();
        sh[threadIdx.x] += u;
        __syncthreads();
    }
    if (i < N) {
        int e = part[blockIdx.x] + sh[threadIdx.x] - v;
        row[i] = e;
        cur[i] = e;
    }
}

__global__ void scatter_kernel(const int* __restrict__ src, const int* __restrict__ dst,
                               int* __restrict__ cur, int* __restrict__ ssrc, int E)
{
    int i = (blockIdx.x * blockDim.x + threadIdx.x) * 4;
    if (i + 3 < E) {
        int4 s = *(const int4*)(src + i);
        int4 d = *(const int4*)(dst + i);
        ssrc[atomicAdd(&cur[d.x], 1)] = s.x;
        ssrc[atomicAdd(&cur[d.y], 1)] = s.y;
        ssrc[atomicAdd(&cur[d.z], 1)] = s.z;
        ssrc[atomicAdd(&cur[d.w], 1)] = s.w;
    } else {
        for (; i < E; ++i) ssrc[atomicAdd(&cur[dst[i]], 1)] = src[i];
    }
}

// ---------------- GAT aggregation core: 4 lanes per node ----------------
template <int F>
__device__ __forceinline__ void gat_agg_core(int n, int lane,
    const int* __restrict__ row, const int* __restrict__ ssrc,
    const float* __restrict__ h, const float* __restrict__ as_, const float* __restrict__ ad_,
    float (&acc)[F], float& denom)
{
    float adn = ad_[n];
    denom = 0.f;
#pragma unroll
    for (int f = 0; f < F; ++f) acc[f] = 0.f;
    if (lane == 0) {  // self-loop contribution (never materialized in edge list)
        float w = __expf(lrelu(as_[n] + adn));
        denom = w;
#pragma unroll
        for (int f = 0; f < F; ++f) acc[f] = w * h[(size_t)n * F + f];
    }
    int beg = row[n], end = row[n + 1];
    for (int j = beg + lane; j < end; j += 4) {
        int s = ssrc[j];
        float w = __expf(lrelu(as_[s] + adn));
        denom += w;
        if (F == 4) {
            float4 hv = ((const float4*)h)[s];
            acc[0] += w * hv.x; acc[1] += w * hv.y; acc[2] += w * hv.z; acc[3] += w * hv.w;
        } else {
            float2 hv = ((const float2*)h)[s];
            acc[0] += w * hv.x; acc[1] += w * hv.y;
        }
    }
#pragma unroll
    for (int m = 1; m < 4; m <<= 1) {
        denom += __shfl_xor(denom, m);
#pragma unroll
        for (int f = 0; f < F; ++f) acc[f] += __shfl_xor(acc[f], m);
    }
}

// layer 1 aggregate (F=4) + fused epilogue: tanh -> out_h1, next h2pre = h1 @ W2 (4x4) + alphas
__global__ void agg_l1_kernel(const int* __restrict__ row, const int* __restrict__ ssrc,
    const float* __restrict__ h, const float* __restrict__ as_, const float* __restrict__ ad_,
    const float* __restrict__ b,
    const float* __restrict__ Wn, const float* __restrict__ ans, const float* __restrict__ andd,
    float* __restrict__ out_h, float* __restrict__ hn, float* __restrict__ asn, float* __restrict__ adn_,
    int N)
{
    int t = blockIdx.x * blockDim.x + threadIdx.x;
    int n = t >> 2, lane = t & 3;
    if (n >= N) return;
    float acc[4]; float denom;
    gat_agg_core<4>(n, lane, row, ssrc, h, as_, ad_, acc, denom);
    if (lane != 0) return;
    float inv = 1.f / denom;
    float hr[4];
#pragma unroll
    for (int f = 0; f < 4; ++f) hr[f] = tanhf(acc[f] * inv + b[f]);
    ((float4*)out_h)[n] = make_float4(hr[0], hr[1], hr[2], hr[3]);
    float hp[4]; float s = 0.f, d = 0.f;
#pragma unroll
    for (int g = 0; g < 4; ++g) {
        float v = hr[0] * Wn[g] + hr[1] * Wn[4 + g] + hr[2] * Wn[8 + g] + hr[3] * Wn[12 + g];
        hp[g] = v; s += v * ans[g]; d += v * andd[g];
    }
    ((float4*)hn)[n] = make_float4(hp[0], hp[1], hp[2], hp[3]);
    asn[n] = s; adn_[n] = d;
}

// layer 2 aggregate (F=4) + fused epilogue: tanh -> out_h2, next h3pre = h2 @ W3 (4x2) + alphas
__global__ void agg_l2_kernel(const int* __restrict__ row, const int* __restrict__ ssrc,
    const float* __restrict__ h, const float* __restrict__ as_, const float* __restrict__ ad_,
    const float* __restrict__ b,
    const float* __restrict__ Wn, const float* __restrict__ ans, const float* __restrict__ andd,
    float* __restrict__ out_h, float* __restrict__ hn, float* __restrict__ asn, float* __restrict__ adn_,
    int N)
{
    int t = blockIdx.x * blockDim.x + threadIdx.x;
    int n = t >> 2, lane = t & 3;
    if (n >= N) return;
    float acc[4]; float denom;
    gat_agg_core<4>(n, lane, row, ssrc, h, as_, ad_, acc, denom);
    if (lane != 0) return;
    float inv = 1.f / denom;
    float hr[4];
#pragma unroll
    for (int f = 0; f < 4; ++f) hr[f] = tanhf(acc[f] * inv + b[f]);
    ((float4*)out_h)[n] = make_float4(hr[0], hr[1], hr[2], hr[3]);
    float hp0 = hr[0] * Wn[0] + hr[1] * Wn[2] + hr[2] * Wn[4] + hr[3] * Wn[6];
    float hp1 = hr[0] * Wn[1] + hr[1] * Wn[3] + hr[2] * Wn[5] + hr[3] * Wn[7];
    ((float2*)hn)[n] = make_float2(hp0, hp1);
    asn[n] = hp0 * ans[0] + hp1 * ans[1];
    adn_[n] = hp0 * andd[0] + hp1 * andd[1];
}

// layer 3 aggregate (F=2) + fused epilogue: tanh -> out_h3, classifier out = h3 @ Wc (2x8) + bc
__global__ void agg_l3_kernel(const int* __restrict__ row, const int* __restrict__ ssrc,
    const float* __restrict__ h, const float* __restrict__ as_, const float* __restrict__ ad_,
    const float* __restrict__ b,
    const float* __restrict__ Wc, const float* __restrict__ bc,
    float* __restrict__ out_h, float* __restrict__ out_c,
    int N)
{
    int t = blockIdx.x * blockDim.x + threadIdx.x;
    int n = t >> 2, lane = t & 3;
    if (n >= N) return;
    float acc[2]; float denom;
    gat_agg_core<2>(n, lane, row, ssrc, h, as_, ad_, acc, denom);
    if (lane != 0) return;
    float inv = 1.f / denom;
    float hr0 = tanhf(acc[0] * inv + b[0]);
    float hr1 = tanhf(acc[1] * inv + b[1]);
    ((float2*)out_h)[n] = make_float2(hr0, hr1);
    float o[8];
#pragma unroll
    for (int c = 0; c < 8; ++c) o[c] = hr0 * Wc[c] + hr1 * Wc[8 + c] + bc[c];
    float4* op = (float4*)(out_c + (size_t)n * 8);
    op[0] = make_float4(o[0], o[1], o[2], o[3]);
    op[1] = make_float4(o[4], o[5], o[6], o[7]);
}

extern "C" void kernel_launch(void* const* d_in, const int* in_sizes, int n_in,
                              void* d_out, int out_size, void* d_ws, size_t ws_size,
                              hipStream_t stream)
{
    const float* x   = (const float*)d_in[0];
    const int*   ei  = (const int*)d_in[1];
    const float* W1  = (const float*)d_in[2];
    const float* a1s = (const float*)d_in[3];
    const float* a1d = (const float*)d_in[4];
    const float* b1  = (const float*)d_in[5];
    const float* W2  = (const float*)d_in[6];
    const float* a2s = (const float*)d_in[7];
    const float* a2d = (const float*)d_in[8];
    const float* b2  = (const float*)d_in[9];
    const float* W3  = (const float*)d_in[10];
    const float* a3s = (const float*)d_in[11];
    const float* a3d = (const float*)d_in[12];
    const float* b3  = (const float*)d_in[13];
    const float* Wc  = (const float*)d_in[14];
    const float* bc  = (const float*)d_in[15];

    const int N = in_sizes[0] / 128;
    const int E = in_sizes[1] / 2;
    const int* src = ei;
    const int* dst = ei + E;

    float* out    = (float*)d_out;
    float* out_h1 = out;                      // [N,4]
    float* out_h2 = out + (size_t)4 * N;      // [N,4]
    float* out_h3 = out + (size_t)8 * N;      // [N,2]
    float* out_c  = out + (size_t)10 * N;     // [N,8]

    // workspace layout (256B-aligned slices)
    char* ws = (char*)d_ws;
    size_t off = 0;
    auto alloc = [&](size_t bytes) -> void* {
        void* p = ws + off;
        off = (off + bytes + 255) & ~(size_t)255;
        return p;
    };
    int*   deg  = (int*)  alloc((size_t)N * 4);
    int*   row  = (int*)  alloc(((size_t)N + 1) * 4);
    int*   cur  = (int*)  alloc((size_t)N * 4);
    int*   part = (int*)  alloc(1024 * 4);
    int*   ssrc = (int*)  alloc((size_t)E * 4);
    float* hA   = (float*)alloc((size_t)N * 4 * 4);
    float* asA  = (float*)alloc((size_t)N * 4);
    float* adA  = (float*)alloc((size_t)N * 4);
    float* hB   = (float*)alloc((size_t)N * 4 * 4);
    float* asB  = (float*)alloc((size_t)N * 4);
    float* adB  = (float*)alloc((size_t)N * 4);
    if (off > ws_size) return;  // workspace too small — bail visibly

    const int nb = (N + 255) / 256;
    const int eb = ((E + 3) / 4 + 255) / 256;
    const int ab = (4 * N + 255) / 256;

    hipMemsetAsync(deg, 0, (size_t)N * 4, stream);
    l1_init_kernel<<<nb, 256, 0, stream>>>(x, W1, a1s, a1d, hA, asA, adA, N);
    hist_kernel<<<eb, 256, 0, stream>>>(dst, deg, E);
    scan_part_kernel<<<nb, 256, 0, stream>>>(deg, part, N);
    scan_top_kernel<<<1, 1024, 0, stream>>>(part, nb, row, N, E);
    scan_final_kernel<<<nb, 256, 0, stream>>>(deg, part, row, cur, N);
    scatter_kernel<<<eb, 256, 0, stream>>>(src, dst, cur, ssrc, E);

    // layer 1: reads hA/asA/adA, writes out_h1 + (hB/asB/adB for layer 2)
    agg_l1_kernel<<<ab, 256, 0, stream>>>(row, ssrc, hA, asA, adA, b1,
                                          W2, a2s, a2d, out_h1, hB, asB, adB, N);
    // layer 2: reads hB/asB/adB, writes out_h2 + (hA[N,2]/asA/adA for layer 3)
    agg_l2_kernel<<<ab, 256, 0, stream>>>(row, ssrc, hB, asB, adB, b2,
                                          W3, a3s, a3d, out_h2, hA, asA, adA, N);
    // layer 3: reads hA[N,2]/asA/adA, writes out_h3 + classifier out
    agg_l3_kernel<<<ab, 256, 0, stream>>>(row, ssrc, hA, asA, adA, b3,
                                          Wc, bc, out_h3, out_c, N);
}

// Round 2
// 616.500 us; speedup vs baseline: 1.6736x; 1.6736x over previous
//
#include <hip/hip_runtime.h>

#define NEG_SLOPE 0.2f
#define BKT_BITS 9
#define BKT_NODES 512            // 1 << BKT_BITS
#define CHUNK 8192
#define AGG_SLICES 8

__device__ __forceinline__ float lrelu(float x) { return x > 0.f ? x : NEG_SLOPE * x; }

// f32 atomic add that maps to hw global_atomic_add_f32 / ds_add_f32 (no CAS loop)
__device__ __forceinline__ void atomAddF(float* p, float v) { unsafeAtomicAdd(p, v); }

// ---------------- Layer-1 init: h1pre = x @ W1 (128x4), alpha_s/alpha_d ----------------
__global__ void l1_init_kernel(const float* __restrict__ x,
                               const float* __restrict__ W1,
                               const float* __restrict__ a_s,
                               const float* __restrict__ a_d,
                               float* __restrict__ h,
                               float* __restrict__ as_,
                               float* __restrict__ ad_,
                               int N)
{
    __shared__ float Wl[512];
    for (int i = threadIdx.x; i < 512; i += blockDim.x) Wl[i] = W1[i];
    __syncthreads();
    int n = blockIdx.x * blockDim.x + threadIdx.x;
    if (n >= N) return;
    const float4* xr = (const float4*)(x + (size_t)n * 128);
    float a0 = 0.f, a1 = 0.f, a2 = 0.f, a3 = 0.f;
#pragma unroll 8
    for (int j = 0; j < 32; ++j) {
        float4 v = xr[j];
        const float* w = &Wl[j * 16];
        a0 += v.x * w[0] + v.y * w[4] + v.z * w[8]  + v.w * w[12];
        a1 += v.x * w[1] + v.y * w[5] + v.z * w[9]  + v.w * w[13];
        a2 += v.x * w[2] + v.y * w[6] + v.z * w[10] + v.w * w[14];
        a3 += v.x * w[3] + v.y * w[7] + v.z * w[11] + v.w * w[15];
    }
    ((float4*)h)[n] = make_float4(a0, a1, a2, a3);
    as_[n] = a0 * a_s[0] + a1 * a_s[1] + a2 * a_s[2] + a3 * a_s[3];
    ad_[n] = a0 * a_d[0] + a1 * a_d[1] + a2 * a_d[2] + a3 * a_d[3];
}

// ---------------- bucket histogram (dst >> BKT_BITS) ----------------
__global__ void bhist_kernel(const int* __restrict__ dst, int* __restrict__ bcnt, int E, int nbkt)
{
    __shared__ int h[256];
    h[threadIdx.x] = 0;
    __syncthreads();
    int base = blockIdx.x * CHUNK;
    int end = min(base + CHUNK, E);
    for (int i = base + threadIdx.x; i < end; i += 256)
        atomicAdd(&h[dst[i] >> BKT_BITS], 1);
    __syncthreads();
    if ((int)threadIdx.x < nbkt && h[threadIdx.x])
        atomicAdd(&bcnt[threadIdx.x], h[threadIdx.x]);
}

// ---------------- bucket offsets scan (single block; nbkt <= 256) ----------------
__global__ void bscan_kernel(const int* __restrict__ bcnt, int* __restrict__ bo,
                             int* __restrict__ gcur, int nbkt, int E)
{
    __shared__ int sh[256];
    int t = threadIdx.x;
    int v = (t < nbkt) ? bcnt[t] : 0;
    sh[t] = v;
    __syncthreads();
    for (int o = 1; o < 256; o <<= 1) {
        int u = (t >= o) ? sh[t - o] : 0;
        __syncthreads();
        sh[t] += u;
        __syncthreads();
    }
    if (t < nbkt) { int e = sh[t] - v; bo[t] = e; gcur[t] = e; }
    if (t == 0) bo[nbkt] = E;
}

// ---------------- LDS-staged bucket scatter: coalesced writes of packed edges ----------------
__global__ void __launch_bounds__(256, 1) bscat_kernel(const int* __restrict__ src,
                                                       const int* __restrict__ dst,
                                                       int* __restrict__ gcur,
                                                       int* __restrict__ packed,
                                                       int E)
{
    __shared__ int hist[256];
    __shared__ int lbase[256];
    __shared__ int gbase[256];
    __shared__ int lcur[256];
    __shared__ int sc[256];
    __shared__ int stage[CHUNK];
    __shared__ unsigned char sbkt[CHUNK];
    int t = threadIdx.x;
    hist[t] = 0; lcur[t] = 0;
    __syncthreads();
    int base = blockIdx.x * CHUNK;
    int end = min(base + CHUNK, E);
    for (int i = base + t; i < end; i += 256)
        atomicAdd(&hist[dst[i] >> BKT_BITS], 1);
    __syncthreads();
    int v = hist[t];
    sc[t] = v;
    __syncthreads();
    for (int o = 1; o < 256; o <<= 1) {
        int u = (t >= o) ? sc[t - o] : 0;
        __syncthreads();
        sc[t] += u;
        __syncthreads();
    }
    lbase[t] = sc[t] - v;
    if (v > 0) gbase[t] = atomicAdd(&gcur[t], v);   // hist[t]==0 for t>=nbkt
    __syncthreads();
    for (int i = base + t; i < end; i += 256) {
        int d = dst[i];
        int b = d >> BKT_BITS;
        int r = atomicAdd(&lcur[b], 1);
        int p = lbase[b] + r;
        stage[p] = src[i] | ((d & (BKT_NODES - 1)) << 17);
        sbkt[p] = (unsigned char)b;
    }
    __syncthreads();
    int cnt = end - base;
    for (int i = t; i < cnt; i += 256) {
        int b = sbkt[i];
        packed[gbase[b] + (i - lbase[b])] = stage[i];
    }
}

// ---------------- bucket-windowed aggregation with LDS f32 atomics ----------------
template <int F>
__global__ void agg_kernel(const int* __restrict__ bo, const int* __restrict__ packed,
                           const float* __restrict__ h, const float* __restrict__ as_,
                           const float* __restrict__ ad_,
                           float* __restrict__ gacc, int N)
{
    __shared__ float acc[BKT_NODES * (F + 1)];
    __shared__ float adl[BKT_NODES];
    int b = blockIdx.x / AGG_SLICES;
    int sl = blockIdx.x % AGG_SLICES;
    int t = threadIdx.x;
    for (int i = t; i < BKT_NODES * (F + 1); i += 256) acc[i] = 0.f;
    int nbase = b << BKT_BITS;
    for (int i = t; i < BKT_NODES; i += 256)
        adl[i] = (nbase + i < N) ? ad_[nbase + i] : 0.f;
    __syncthreads();
    int beg = bo[b], end = bo[b + 1];
    int cnt = end - beg;
    int per = (cnt + AGG_SLICES - 1) / AGG_SLICES;
    int s0 = beg + sl * per;
    int s1 = min(s0 + per, end);
    for (int i = s0 + t; i < s1; i += 256) {
        int p = packed[i];
        int s = p & 0x1FFFF;
        int ld = p >> 17;
        float w = __expf(lrelu(as_[s] + adl[ld]));
        float* a = &acc[ld * (F + 1)];
        if (F == 4) {
            float4 hv = ((const float4*)h)[s];
            atomAddF(a + 0, w * hv.x); atomAddF(a + 1, w * hv.y);
            atomAddF(a + 2, w * hv.z); atomAddF(a + 3, w * hv.w);
        } else {
            float2 hv = ((const float2*)h)[s];
            atomAddF(a + 0, w * hv.x); atomAddF(a + 1, w * hv.y);
        }
        atomAddF(a + F, w);
    }
    __syncthreads();
    for (int i = t; i < BKT_NODES * (F + 1); i += 256) {
        int node = nbase + i / (F + 1);
        if (node < N) {
            float v = acc[i];
            if (v != 0.f) atomAddF(&gacc[(size_t)node * (F + 1) + i % (F + 1)], v);
        }
    }
}

// ---------------- finalize layers 1,2: self-loop + normalize + tanh + next-layer fuse ----------------
template <int FO>
__global__ void finA_kernel(const float* __restrict__ gacc, const float* __restrict__ h,
                            const float* __restrict__ as_, const float* __restrict__ ad_,
                            const float* __restrict__ bias,
                            const float* __restrict__ Wn, const float* __restrict__ ans,
                            const float* __restrict__ andd,
                            float* __restrict__ out_h, float* __restrict__ hn,
                            float* __restrict__ asn, float* __restrict__ adn_, int N)
{
    int n = blockIdx.x * blockDim.x + threadIdx.x;
    if (n >= N) return;
    float w0 = __expf(lrelu(as_[n] + ad_[n]));
    float4 hv = ((const float4*)h)[n];
    const float* g = &gacc[(size_t)n * 5];
    float inv = 1.f / (g[4] + w0);
    float hr[4];
    hr[0] = tanhf((g[0] + w0 * hv.x) * inv + bias[0]);
    hr[1] = tanhf((g[1] + w0 * hv.y) * inv + bias[1]);
    hr[2] = tanhf((g[2] + w0 * hv.z) * inv + bias[2]);
    hr[3] = tanhf((g[3] + w0 * hv.w) * inv + bias[3]);
    ((float4*)out_h)[n] = make_float4(hr[0], hr[1], hr[2], hr[3]);
    if (FO == 4) {
        float hp[4]; float s = 0.f, d = 0.f;
#pragma unroll
        for (int q = 0; q < 4; ++q) {
            float v = hr[0] * Wn[q] + hr[1] * Wn[4 + q] + hr[2] * Wn[8 + q] + hr[3] * Wn[12 + q];
            hp[q] = v; s += v * ans[q]; d += v * andd[q];
        }
        ((float4*)hn)[n] = make_float4(hp[0], hp[1], hp[2], hp[3]);
        asn[n] = s; adn_[n] = d;
    } else {
        float hp0 = hr[0] * Wn[0] + hr[1] * Wn[2] + hr[2] * Wn[4] + hr[3] * Wn[6];
        float hp1 = hr[0] * Wn[1] + hr[1] * Wn[3] + hr[2] * Wn[5] + hr[3] * Wn[7];
        ((float2*)hn)[n] = make_float2(hp0, hp1);
        asn[n] = hp0 * ans[0] + hp1 * ans[1];
        adn_[n] = hp0 * andd[0] + hp1 * andd[1];
    }
}

// ---------------- finalize layer 3: tanh + classifier ----------------
__global__ void finC_kernel(const float* __restrict__ gacc, const float* __restrict__ h,
                            const float* __restrict__ as_, const float* __restrict__ ad_,
                            const float* __restrict__ bias,
                            const float* __restrict__ Wc, const float* __restrict__ bc,
                            float* __restrict__ out_h, float* __restrict__ out_c, int N)
{
    int n = blockIdx.x * blockDim.x + threadIdx.x;
    if (n >= N) return;
    float w0 = __expf(lrelu(as_[n] + ad_[n]));
    float2 hv = ((const float2*)h)[n];
    const float* g = &gacc[(size_t)n * 3];
    float inv = 1.f / (g[2] + w0);
    float hr0 = tanhf((g[0] + w0 * hv.x) * inv + bias[0]);
    float hr1 = tanhf((g[1] + w0 * hv.y) * inv + bias[1]);
    ((float2*)out_h)[n] = make_float2(hr0, hr1);
    float o[8];
#pragma unroll
    for (int c = 0; c < 8; ++c) o[c] = hr0 * Wc[c] + hr1 * Wc[8 + c] + bc[c];
    float4* op = (float4*)(out_c + (size_t)n * 8);
    op[0] = make_float4(o[0], o[1], o[2], o[3]);
    op[1] = make_float4(o[4], o[5], o[6], o[7]);
}

extern "C" void kernel_launch(void* const* d_in, const int* in_sizes, int n_in,
                              void* d_out, int out_size, void* d_ws, size_t ws_size,
                              hipStream_t stream)
{
    const float* x   = (const float*)d_in[0];
    const int*   ei  = (const int*)d_in[1];
    const float* W1  = (const float*)d_in[2];
    const float* a1s = (const float*)d_in[3];
    const float* a1d = (const float*)d_in[4];
    const float* b1  = (const float*)d_in[5];
    const float* W2  = (const float*)d_in[6];
    const float* a2s = (const float*)d_in[7];
    const float* a2d = (const float*)d_in[8];
    const float* b2  = (const float*)d_in[9];
    const float* W3  = (const float*)d_in[10];
    const float* a3s = (const float*)d_in[11];
    const float* a3d = (const float*)d_in[12];
    const float* b3  = (const float*)d_in[13];
    const float* Wc  = (const float*)d_in[14];
    const float* bc  = (const float*)d_in[15];

    const int N = in_sizes[0] / 128;
    const int E = in_sizes[1] / 2;
    const int* src = ei;
    const int* dst = ei + E;
    const int nbkt = (N + BKT_NODES - 1) >> BKT_BITS;      // 196 for N=100k (must be <=256)
    const int nchunks = (E + CHUNK - 1) / CHUNK;

    float* out    = (float*)d_out;
    float* out_h1 = out;
    float* out_h2 = out + (size_t)4 * N;
    float* out_h3 = out + (size_t)8 * N;
    float* out_c  = out + (size_t)10 * N;

    char* ws = (char*)d_ws;
    size_t off = 0;
    auto alloc = [&](size_t bytes) -> void* {
        void* p = ws + off;
        off = (off + bytes + 255) & ~(size_t)255;
        return p;
    };
    int*   bcnt   = (int*)  alloc(256 * 4);
    int*   bo     = (int*)  alloc(257 * 4);
    int*   gcur   = (int*)  alloc(256 * 4);
    int*   packed = (int*)  alloc((size_t)E * 4);
    float* hA     = (float*)alloc((size_t)N * 4 * 4);
    float* asA    = (float*)alloc((size_t)N * 4);
    float* adA    = (float*)alloc((size_t)N * 4);
    float* hB     = (float*)alloc((size_t)N * 4 * 4);
    float* asB    = (float*)alloc((size_t)N * 4);
    float* adB    = (float*)alloc((size_t)N * 4);
    float* gacc   = (float*)alloc((size_t)N * 5 * 4);
    if (off > ws_size) return;  // workspace too small — bail visibly

    const int nb = (N + 255) / 256;

    hipMemsetAsync(bcnt, 0, 256 * 4, stream);
    l1_init_kernel<<<nb, 256, 0, stream>>>(x, W1, a1s, a1d, hA, asA, adA, N);
    bhist_kernel<<<nchunks, 256, 0, stream>>>(dst, bcnt, E, nbkt);
    bscan_kernel<<<1, 256, 0, stream>>>(bcnt, bo, gcur, nbkt, E);
    bscat_kernel<<<nchunks, 256, 0, stream>>>(src, dst, gcur, packed, E);

    // layer 1
    hipMemsetAsync(gacc, 0, (size_t)N * 5 * 4, stream);
    agg_kernel<4><<<nbkt * AGG_SLICES, 256, 0, stream>>>(bo, packed, hA, asA, adA, gacc, N);
    finA_kernel<4><<<nb, 256, 0, stream>>>(gacc, hA, asA, adA, b1, W2, a2s, a2d,
                                           out_h1, hB, asB, adB, N);
    // layer 2 (writes hA reused as [N,2] input of layer 3)
    hipMemsetAsync(gacc, 0, (size_t)N * 5 * 4, stream);
    agg_kernel<4><<<nbkt * AGG_SLICES, 256, 0, stream>>>(bo, packed, hB, asB, adB, gacc, N);
    finA_kernel<2><<<nb, 256, 0, stream>>>(gacc, hB, asB, adB, b2, W3, a3s, a3d,
                                           out_h2, hA, asA, adA, N);
    // layer 3
    hipMemsetAsync(gacc, 0, (size_t)N * 5 * 4, stream);
    agg_kernel<2><<<nbkt * AGG_SLICES, 256, 0, stream>>>(bo, packed, hA, asA, adA, gacc, N);
    finC_kernel<<<nb, 256, 0, stream>>>(gacc, hA, asA, adA, b3, Wc, bc, out_h3, out_c, N);
}

// Round 3
// 589.410 us; speedup vs baseline: 1.7505x; 1.0460x over previous
//
#include <hip/hip_runtime.h>

#define NEG_SLOPE 0.2f
#define BKT_BITS 9
#define BKT_NODES 512            // 1 << BKT_BITS
#define CHUNK 8192
#define AGG_SLICES 16

__device__ __forceinline__ float lrelu(float x) { return x > 0.f ? x : NEG_SLOPE * x; }

// f32 atomic add mapping to hw ds_add_f32 / global_atomic_add_f32 (no CAS loop)
__device__ __forceinline__ void atomAddF(float* p, float v) { unsafeAtomicAdd(p, v); }

// per-node record load: F=4 -> stride 8 {h0..h3, as, pad3}; F=2 -> stride 4 {h0,h1,as,pad}
template <int F>
__device__ __forceinline__ void loadRec(const float* __restrict__ rec, int s, float4& h, float& a)
{
    if (F == 4) {
        h = *(const float4*)(rec + (size_t)s * 8);
        a = rec[(size_t)s * 8 + 4];          // same 32B half-line as h -> L1 hit
    } else {
        float4 r = *(const float4*)(rec + (size_t)s * 4);
        h = r; a = r.z;
    }
}

// ---------------- Layer-1 init: h1pre = x @ W1 (128x4) -> rec {h,as}, ad ----------------
__global__ void l1_init_kernel(const float* __restrict__ x,
                               const float* __restrict__ W1,
                               const float* __restrict__ a_s,
                               const float* __restrict__ a_d,
                               float* __restrict__ rec,
                               float* __restrict__ ad_,
                               int N)
{
    __shared__ float Wl[512];
    for (int i = threadIdx.x; i < 512; i += blockDim.x) Wl[i] = W1[i];
    __syncthreads();
    int n = blockIdx.x * blockDim.x + threadIdx.x;
    if (n >= N) return;
    const float4* xr = (const float4*)(x + (size_t)n * 128);
    float a0 = 0.f, a1 = 0.f, a2 = 0.f, a3 = 0.f;
#pragma unroll 8
    for (int j = 0; j < 32; ++j) {
        float4 v = xr[j];
        const float* w = &Wl[j * 16];
        a0 += v.x * w[0] + v.y * w[4] + v.z * w[8]  + v.w * w[12];
        a1 += v.x * w[1] + v.y * w[5] + v.z * w[9]  + v.w * w[13];
        a2 += v.x * w[2] + v.y * w[6] + v.z * w[10] + v.w * w[14];
        a3 += v.x * w[3] + v.y * w[7] + v.z * w[11] + v.w * w[15];
    }
    float asv = a0 * a_s[0] + a1 * a_s[1] + a2 * a_s[2] + a3 * a_s[3];
    ((float4*)rec)[2 * n]     = make_float4(a0, a1, a2, a3);
    ((float4*)rec)[2 * n + 1] = make_float4(asv, 0.f, 0.f, 0.f);
    ad_[n] = a0 * a_d[0] + a1 * a_d[1] + a2 * a_d[2] + a3 * a_d[3];
}

// ---------------- bucket histogram (dst >> BKT_BITS) ----------------
__global__ void bhist_kernel(const int* __restrict__ dst, int* __restrict__ bcnt, int E, int nbkt)
{
    __shared__ int h[256];
    h[threadIdx.x] = 0;
    __syncthreads();
    int base = blockIdx.x * CHUNK;
    int end = min(base + CHUNK, E);
    for (int i = base + threadIdx.x; i < end; i += 256)
        atomicAdd(&h[dst[i] >> BKT_BITS], 1);
    __syncthreads();
    if ((int)threadIdx.x < nbkt && h[threadIdx.x])
        atomicAdd(&bcnt[threadIdx.x], h[threadIdx.x]);
}

// ---------------- bucket offsets scan (single block; nbkt <= 256) ----------------
__global__ void bscan_kernel(const int* __restrict__ bcnt, int* __restrict__ bo,
                             int* __restrict__ gcur, int nbkt, int E)
{
    __shared__ int sh[256];
    int t = threadIdx.x;
    int v = (t < nbkt) ? bcnt[t] : 0;
    sh[t] = v;
    __syncthreads();
    for (int o = 1; o < 256; o <<= 1) {
        int u = (t >= o) ? sh[t - o] : 0;
        __syncthreads();
        sh[t] += u;
        __syncthreads();
    }
    if (t < nbkt) { int e = sh[t] - v; bo[t] = e; gcur[t] = e; }
    if (t == 0) bo[nbkt] = E;
}

// ---------------- LDS-staged bucket scatter: coalesced writes of packed edges ----------------
__global__ void __launch_bounds__(256, 1) bscat_kernel(const int* __restrict__ src,
                                                       const int* __restrict__ dst,
                                                       int* __restrict__ gcur,
                                                       int* __restrict__ packed,
                                                       int E)
{
    __shared__ int hist[256];
    __shared__ int lbase[256];
    __shared__ int gbase[256];
    __shared__ int lcur[256];
    __shared__ int sc[256];
    __shared__ int stage[CHUNK];
    __shared__ unsigned char sbkt[CHUNK];
    int t = threadIdx.x;
    hist[t] = 0; lcur[t] = 0;
    __syncthreads();
    int base = blockIdx.x * CHUNK;
    int end = min(base + CHUNK, E);
    for (int i = base + t; i < end; i += 256)
        atomicAdd(&hist[dst[i] >> BKT_BITS], 1);
    __syncthreads();
    int v = hist[t];
    sc[t] = v;
    __syncthreads();
    for (int o = 1; o < 256; o <<= 1) {
        int u = (t >= o) ? sc[t - o] : 0;
        __syncthreads();
        sc[t] += u;
        __syncthreads();
    }
    lbase[t] = sc[t] - v;
    if (v > 0) gbase[t] = atomicAdd(&gcur[t], v);   // hist[t]==0 for t>=nbkt
    __syncthreads();
    for (int i = base + t; i < end; i += 256) {
        int d = dst[i];
        int b = d >> BKT_BITS;
        int r = atomicAdd(&lcur[b], 1);
        int p = lbase[b] + r;
        stage[p] = src[i] | ((d & (BKT_NODES - 1)) << 17);
        sbkt[p] = (unsigned char)b;
    }
    __syncthreads();
    int cnt = end - base;
    for (int i = t; i < cnt; i += 256) {
        int b = sbkt[i];
        packed[gbase[b] + (i - lbase[b])] = stage[i];
    }
}

// ---------------- bucket-windowed aggregation, 4-edge batched MLP ----------------
template <int F>
__global__ void agg_kernel(const int* __restrict__ bo, const int* __restrict__ packed,
                           const float* __restrict__ rec, const float* __restrict__ ad_,
                           float* __restrict__ gacc, int N)
{
    __shared__ float acc[BKT_NODES * (F + 1)];
    __shared__ float adl[BKT_NODES];
    int b = blockIdx.x / AGG_SLICES;
    int sl = blockIdx.x % AGG_SLICES;
    int t = threadIdx.x;
    for (int i = t; i < BKT_NODES * (F + 1); i += 256) acc[i] = 0.f;
    int nbase = b << BKT_BITS;
    for (int i = t; i < BKT_NODES; i += 256)
        adl[i] = (nbase + i < N) ? ad_[nbase + i] : 0.f;
    __syncthreads();
    int beg = bo[b], end = bo[b + 1];
    int cnt = end - beg;
    int per = (cnt + AGG_SLICES - 1) / AGG_SLICES;
    int s0 = beg + sl * per;
    int s1 = min(s0 + per, end);
    for (int i = s0 + t; i < s1; i += 1024) {
        // 4 strided, coalesced packed loads (sentinel -1 past end)
        int p0 = packed[i];
        int p1 = (i + 256 < s1) ? packed[i + 256] : -1;
        int p2 = (i + 512 < s1) ? packed[i + 512] : -1;
        int p3 = (i + 768 < s1) ? packed[i + 768] : -1;
        float4 h0, h1, h2, h3;
        float a0, a1, a2, a3;
        // issue all gathers before any consumption (4 independent lines in flight)
        if (p0 >= 0) loadRec<F>(rec, p0 & 0x1FFFF, h0, a0);
        if (p1 >= 0) loadRec<F>(rec, p1 & 0x1FFFF, h1, a1);
        if (p2 >= 0) loadRec<F>(rec, p2 & 0x1FFFF, h2, a2);
        if (p3 >= 0) loadRec<F>(rec, p3 & 0x1FFFF, h3, a3);
        // consume
        if (p0 >= 0) {
            int ld = p0 >> 17;
            float w = __expf(lrelu(a0 + adl[ld]));
            float* a = &acc[ld * (F + 1)];
            atomAddF(a + 0, w * h0.x); atomAddF(a + 1, w * h0.y);
            if (F == 4) { atomAddF(a + 2, w * h0.z); atomAddF(a + 3, w * h0.w); }
            atomAddF(a + F, w);
        }
        if (p1 >= 0) {
            int ld = p1 >> 17;
            float w = __expf(lrelu(a1 + adl[ld]));
            float* a = &acc[ld * (F + 1)];
            atomAddF(a + 0, w * h1.x); atomAddF(a + 1, w * h1.y);
            if (F == 4) { atomAddF(a + 2, w * h1.z); atomAddF(a + 3, w * h1.w); }
            atomAddF(a + F, w);
        }
        if (p2 >= 0) {
            int ld = p2 >> 17;
            float w = __expf(lrelu(a2 + adl[ld]));
            float* a = &acc[ld * (F + 1)];
            atomAddF(a + 0, w * h2.x); atomAddF(a + 1, w * h2.y);
            if (F == 4) { atomAddF(a + 2, w * h2.z); atomAddF(a + 3, w * h2.w); }
            atomAddF(a + F, w);
        }
        if (p3 >= 0) {
            int ld = p3 >> 17;
            float w = __expf(lrelu(a3 + adl[ld]));
            float* a = &acc[ld * (F + 1)];
            atomAddF(a + 0, w * h3.x); atomAddF(a + 1, w * h3.y);
            if (F == 4) { atomAddF(a + 2, w * h3.z); atomAddF(a + 3, w * h3.w); }
            atomAddF(a + F, w);
        }
    }
    __syncthreads();
    for (int i = t; i < BKT_NODES * (F + 1); i += 256) {
        int node = nbase + i / (F + 1);
        if (node < N) {
            float v = acc[i];
            if (v != 0.f) atomAddF(&gacc[(size_t)node * (F + 1) + i % (F + 1)], v);
        }
    }
}

// ---------------- finalize layers 1,2: self-loop + normalize + tanh + next-layer fuse ----------------
template <int FO>
__global__ void finA_kernel(const float* __restrict__ gacc, const float* __restrict__ rec,
                            const float* __restrict__ ad_,
                            const float* __restrict__ bias,
                            const float* __restrict__ Wn, const float* __restrict__ ans,
                            const float* __restrict__ andd,
                            float* __restrict__ out_h, float* __restrict__ recn,
                            float* __restrict__ adn_, int N)
{
    int n = blockIdx.x * blockDim.x + threadIdx.x;
    if (n >= N) return;
    float4 hv = ((const float4*)rec)[2 * n];
    float asv = rec[(size_t)n * 8 + 4];
    float w0 = __expf(lrelu(asv + ad_[n]));
    const float* g = &gacc[(size_t)n * 5];
    float inv = 1.f / (g[4] + w0);
    float hr[4];
    hr[0] = tanhf((g[0] + w0 * hv.x) * inv + bias[0]);
    hr[1] = tanhf((g[1] + w0 * hv.y) * inv + bias[1]);
    hr[2] = tanhf((g[2] + w0 * hv.z) * inv + bias[2]);
    hr[3] = tanhf((g[3] + w0 * hv.w) * inv + bias[3]);
    ((float4*)out_h)[n] = make_float4(hr[0], hr[1], hr[2], hr[3]);
    if (FO == 4) {
        float hp[4]; float s = 0.f, d = 0.f;
#pragma unroll
        for (int q = 0; q < 4; ++q) {
            float v = hr[0] * Wn[q] + hr[1] * Wn[4 + q] + hr[2] * Wn[8 + q] + hr[3] * Wn[12 + q];
            hp[q] = v; s += v * ans[q]; d += v * andd[q];
        }
        ((float4*)recn)[2 * n]     = make_float4(hp[0], hp[1], hp[2], hp[3]);
        ((float4*)recn)[2 * n + 1] = make_float4(s, 0.f, 0.f, 0.f);
        adn_[n] = hr[0] * 0.f + d;  // d
    } else {
        float hp0 = hr[0] * Wn[0] + hr[1] * Wn[2] + hr[2] * Wn[4] + hr[3] * Wn[6];
        float hp1 = hr[0] * Wn[1] + hr[1] * Wn[3] + hr[2] * Wn[5] + hr[3] * Wn[7];
        float s = hp0 * ans[0] + hp1 * ans[1];
        ((float4*)recn)[n] = make_float4(hp0, hp1, s, 0.f);
        adn_[n] = hp0 * andd[0] + hp1 * andd[1];
    }
}

// ---------------- finalize layer 3: tanh + classifier ----------------
__global__ void finC_kernel(const float* __restrict__ gacc, const float* __restrict__ rec,
                            const float* __restrict__ ad_,
                            const float* __restrict__ bias,
                            const float* __restrict__ Wc, const float* __restrict__ bc,
                            float* __restrict__ out_h, float* __restrict__ out_c, int N)
{
    int n = blockIdx.x * blockDim.x + threadIdx.x;
    if (n >= N) return;
    float4 r = ((const float4*)rec)[n];     // {h0,h1,as,pad}
    float w0 = __expf(lrelu(r.z + ad_[n]));
    const float* g = &gacc[(size_t)n * 3];
    float inv = 1.f / (g[2] + w0);
    float hr0 = tanhf((g[0] + w0 * r.x) * inv + bias[0]);
    float hr1 = tanhf((g[1] + w0 * r.y) * inv + bias[1]);
    ((float2*)out_h)[n] = make_float2(hr0, hr1);
    float o[8];
#pragma unroll
    for (int c = 0; c < 8; ++c) o[c] = hr0 * Wc[c] + hr1 * Wc[8 + c] + bc[c];
    float4* op = (float4*)(out_c + (size_t)n * 8);
    op[0] = make_float4(o[0], o[1], o[2], o[3]);
    op[1] = make_float4(o[4], o[5], o[6], o[7]);
}

extern "C" void kernel_launch(void* const* d_in, const int* in_sizes, int n_in,
                              void* d_out, int out_size, void* d_ws, size_t ws_size,
                              hipStream_t stream)
{
    const float* x   = (const float*)d_in[0];
    const int*   ei  = (const int*)d_in[1];
    const float* W1  = (const float*)d_in[2];
    const float* a1s = (const float*)d_in[3];
    const float* a1d = (const float*)d_in[4];
    const float* b1  = (const float*)d_in[5];
    const float* W2  = (const float*)d_in[6];
    const float* a2s = (const float*)d_in[7];
    const float* a2d = (const float*)d_in[8];
    const float* b2  = (const float*)d_in[9];
    const float* W3  = (const float*)d_in[10];
    const float* a3s = (const float*)d_in[11];
    const float* a3d = (const float*)d_in[12];
    const float* b3  = (const float*)d_in[13];
    const float* Wc  = (const float*)d_in[14];
    const float* bc  = (const float*)d_in[15];

    const int N = in_sizes[0] / 128;
    const int E = in_sizes[1] / 2;
    const int* src = ei;
    const int* dst = ei + E;
    const int nbkt = (N + BKT_NODES - 1) >> BKT_BITS;      // 196 for N=100k (<=256)
    const int nchunks = (E + CHUNK - 1) / CHUNK;

    float* out    = (float*)d_out;
    float* out_h1 = out;
    float* out_h2 = out + (size_t)4 * N;
    float* out_h3 = out + (size_t)8 * N;
    float* out_c  = out + (size_t)10 * N;

    char* ws = (char*)d_ws;
    size_t off = 0;
    auto alloc = [&](size_t bytes) -> void* {
        void* p = ws + off;
        off = (off + bytes + 255) & ~(size_t)255;
        return p;
    };
    int*   bcnt   = (int*)  alloc(256 * 4);
    int*   bo     = (int*)  alloc(257 * 4);
    int*   gcur   = (int*)  alloc(256 * 4);
    int*   packed = (int*)  alloc((size_t)E * 4);
    float* recA   = (float*)alloc((size_t)N * 8 * 4);
    float* adA    = (float*)alloc((size_t)N * 4);
    float* recB   = (float*)alloc((size_t)N * 8 * 4);
    float* adB    = (float*)alloc((size_t)N * 4);
    float* gacc   = (float*)alloc((size_t)N * 5 * 4);
    if (off > ws_size) return;  // workspace too small — bail visibly

    const int nb = (N + 255) / 256;

    hipMemsetAsync(bcnt, 0, 256 * 4, stream);
    l1_init_kernel<<<nb, 256, 0, stream>>>(x, W1, a1s, a1d, recA, adA, N);
    bhist_kernel<<<nchunks, 256, 0, stream>>>(dst, bcnt, E, nbkt);
    bscan_kernel<<<1, 256, 0, stream>>>(bcnt, bo, gcur, nbkt, E);
    bscat_kernel<<<nchunks, 256, 0, stream>>>(src, dst, gcur, packed, E);

    // layer 1
    hipMemsetAsync(gacc, 0, (size_t)N * 5 * 4, stream);
    agg_kernel<4><<<nbkt * AGG_SLICES, 256, 0, stream>>>(bo, packed, recA, adA, gacc, N);
    finA_kernel<4><<<nb, 256, 0, stream>>>(gacc, recA, adA, b1, W2, a2s, a2d,
                                           out_h1, recB, adB, N);
    // layer 2 (recA reused as layer-3 input records, stride 4)
    hipMemsetAsync(gacc, 0, (size_t)N * 5 * 4, stream);
    agg_kernel<4><<<nbkt * AGG_SLICES, 256, 0, stream>>>(bo, packed, recB, adB, gacc, N);
    finA_kernel<2><<<nb, 256, 0, stream>>>(gacc, recB, adB, b2, W3, a3s, a3d,
                                           out_h2, recA, adA, N);
    // layer 3
    hipMemsetAsync(gacc, 0, (size_t)N * 5 * 4, stream);
    agg_kernel<2><<<nbkt * AGG_SLICES, 256, 0, stream>>>(bo, packed, recA, adA, gacc, N);
    finC_kernel<<<nb, 256, 0, stream>>>(gacc, recA, adA, b3, Wc, bc, out_h3, out_c, N);
}